// Round 7
// baseline (623.900 us; speedup 1.0000x reference)
//
#include <hip/hip_runtime.h>
#include <hip/hip_bf16.h>

// NEmbNet R7: m201-style 256x256 8-phase GEMM (T2 swizzle + T3/T4 counted vmcnt
// + T5 setprio), interleaved wave tiling so half-tile staggered prefetch is
// provably safe: stage order A0,B0,B1,A1 == first-need order; vmcnt(4) at
// phase ends 1,2,4; in-flight 4..8 loads, never drained in-loop.
// Rest (layout, swizzle, gemm2, cvt, ident) frozen from R6 (passed 2x).

typedef short v8s __attribute__((ext_vector_type(8)));
typedef float v4f __attribute__((ext_vector_type(4)));
using bf16 = __hip_bfloat16;

#define AS_GLOBAL __attribute__((address_space(1)))
#define AS_LDS    __attribute__((address_space(3)))

static constexpr int Mtot = 8192;
static constexpr int Fdim = 512;
static constexpr int Hdim = 1024;
static constexpr int Pdim = 64;
static constexpr int Aexp = 16;

__device__ __forceinline__ void gload_lds16(const void* g, void* l) {
  __builtin_amdgcn_global_load_lds((const AS_GLOBAL void*)g, (AS_LDS void*)l, 16, 0, 0);
}
__device__ __forceinline__ unsigned short bfu(float x) {
  bf16 h = __float2bfloat16(x);
  return *(unsigned short*)&h;
}
#define MFMA16(d, a, b) d = __builtin_amdgcn_mfma_f32_16x16x32_bf16(a, b, d, 0, 0, 0)
#define WAIT_VM4 asm volatile("s_waitcnt vmcnt(4)" ::: "memory")
#define WAIT_VM3 asm volatile("s_waitcnt vmcnt(3)" ::: "memory")
#define WAIT_VM2 asm volatile("s_waitcnt vmcnt(2)" ::: "memory")
#define WAIT_VM0 asm volatile("s_waitcnt vmcnt(0)" ::: "memory")
#define WAIT_LGKM0 asm volatile("s_waitcnt lgkmcnt(0)" ::: "memory")
#define BAR() __builtin_amdgcn_s_barrier()

__device__ __forceinline__ void cvt_span(const float* __restrict__ src,
                                         unsigned short* __restrict__ dst, int n4,
                                         int gid, int nthr) {
  for (int i = gid; i < n4; i += nthr) {
    float4 v = ((const float4*)src)[i];
    ushort4 u;
    u.x = bfu(v.x); u.y = bfu(v.y); u.z = bfu(v.z); u.w = bfu(v.w);
    ((ushort4*)dst)[i] = u;
  }
}

// ---------------------------------------------------------------- cvt all inputs
__global__ void cvt_all_kernel(const float* __restrict__ s0, unsigned short* __restrict__ d0, int n0,
                               const float* __restrict__ s1, unsigned short* __restrict__ d1, int n1,
                               const float* __restrict__ s2, unsigned short* __restrict__ d2, int n2,
                               const float* __restrict__ s3, unsigned short* __restrict__ d3, int n3) {
  int gid = blockIdx.x * blockDim.x + threadIdx.x;
  int nthr = gridDim.x * blockDim.x;
  cvt_span(s0, d0, n0, gid, nthr);
  cvt_span(s1, d1, n1, gid, nthr);
  cvt_span(s2, d2, n2, gid, nthr);
  cvt_span(s3, d3, n3, gid, nthr);
}

// ---------------------------------------------------------------- identity fill
__global__ void ident_kernel(float* __restrict__ outp) {
  const long total4 = (long)Mtot * Pdim * Pdim / 4;
  long i = blockIdx.x * 256 + threadIdx.x;
  const long stride = (long)gridDim.x * 256;
  for (; i < total4; i += stride) {
    long e = i * 4;
    int q = (int)(e & 63);
    int p = (int)((e >> 6) & 63);
    float4 v;
    v.x = (p == q) ? 1.f : 0.f;
    v.y = (p == q + 1) ? 1.f : 0.f;
    v.z = (p == q + 2) ? 1.f : 0.f;
    v.w = (p == q + 3) ? 1.f : 0.f;
    *(float4*)&outp[e] = v;
  }
}

// ---------------------------------------------------------------- 256x256 8-phase GEMM
// C[g, m-tile, n-tile] = relu(A @ B^T + bias). BK=64, 8 waves (wm 0..1, wn 0..3).
// Interleaved wave tile: wave owns rows {mf8*32 + wm*16 + 0..15, mf8 0..7},
//                        cols {nf*64 + wn*16 + 0..15, nf 0..3}.
// => phase (mh,nh) touches exactly A-half mh, B-half nh for EVERY wave.
// Double-buffered LDS (128KB). Per K-tile 4 phases; stage kt+1 halves in
// need-order A0,B0,B1,A1; vmcnt(4) at ends of ph1,ph2,ph4.
template <int NT>  // K = NT*64, A row stride == K
__global__ __launch_bounds__(512, 2) void gemm256_kernel(
    const bf16* __restrict__ Ain, long aAmul,
    const bf16* __restrict__ Bw,
    const float* __restrict__ bias,
    bf16* __restrict__ Cout, long aCmul, int nbm) {
  constexpr int K = NT * 64;
  __shared__ short sA[2][256 * 64];
  __shared__ short sB[2][256 * 64];
  const int t = threadIdx.x;
  const int nwg = nbm * 4 * Aexp;
  const int flat = blockIdx.x;
  const int perx = nwg >> 3;
  const int swz = (flat & 7) * perx + (flat >> 3);
  const int perg = nbm * 4;
  const int g = swz / perg;
  const int e = swz % perg;
  const int mt = e >> 2;   // n fastest: A-tile reused across 4 n-tiles, B panel L2-resident
  const int nt = e & 3;
  const int mBase = mt * 256, nBase = nt * 256;

  const bf16* A0 = Ain + (size_t)g * aAmul;
  const bf16* B0 = Bw + (size_t)g * (1024 * K);
  const float* biasE = bias + g * 1024 + nBase;
  bf16* C0 = Cout + (size_t)g * aCmul;

  const int w = t >> 6, lane = t & 63;
  const int wm = w & 1, wn = w >> 1;
  const int lr = lane & 15, lk = lane >> 4;

  // staging (T2: pre-swizzled global source granule, linear LDS dest)
  const int srow = t >> 3;                 // 0..63
  const int sg = (t & 7) ^ (srow & 7);
  const bf16* gA = A0 + (size_t)(mBase + srow) * K + sg * 8;
  const bf16* gB = B0 + (size_t)(nBase + srow) * K + sg * 8;
  auto stA = [&](int bufi, int half, int i, int kt) {
    gload_lds16(gA + (size_t)(half * 128 + i * 64) * K + kt * 64,
                &sA[bufi][(half * 128 + i * 64) * 64 + t * 8]);
  };
  auto stB = [&](int bufi, int half, int i, int kt) {
    gload_lds16(gB + (size_t)(half * 128 + i * 64) * K + kt * 64,
                &sB[bufi][(half * 128 + i * 64) * 64 + t * 8]);
  };

  v4f acc[8][4];
#pragma unroll
  for (int m = 0; m < 8; ++m)
#pragma unroll
    for (int n = 0; n < 4; ++n) acc[m][n] = (v4f)(0.f);

  v8s a[4][2], b[2][2];
  const int xg = lr & 7;  // swizzle XOR term (row&7 == lr&7 for all frag rows)

  // prologue: K-tile 0 fully into buf0
  stA(0, 0, 0, 0); stA(0, 0, 1, 0);
  stB(0, 0, 0, 0); stB(0, 0, 1, 0);
  stB(0, 1, 0, 0); stB(0, 1, 1, 0);
  stA(0, 1, 0, 0); stA(0, 1, 1, 0);
  WAIT_VM0;
  BAR();

  for (int kt = 0; kt < NT; ++kt) {
    const int cur = kt & 1, nb = cur ^ 1;
    const bool pf = (kt + 1) < NT;
    const short* cA = sA[cur];
    const short* cB = sB[cur];

    auto rdA = [&](int mh) {
#pragma unroll
      for (int mf = 0; mf < 4; ++mf)
#pragma unroll
        for (int ks = 0; ks < 2; ++ks) {
          const int row = (mh * 4 + mf) * 32 + wm * 16 + lr;
          a[mf][ks] = *(const v8s*)&cA[row * 64 + (((ks * 4 + lk) ^ xg) << 3)];
        }
    };
    auto rdB = [&](int nh) {
#pragma unroll
      for (int nf = 0; nf < 2; ++nf)
#pragma unroll
        for (int ks = 0; ks < 2; ++ks) {
          const int row = (nh * 2 + nf) * 64 + wn * 16 + lr;
          b[nf][ks] = *(const v8s*)&cB[row * 64 + (((ks * 4 + lk) ^ xg) << 3)];
        }
    };

    // ---- PH1 (mh0,nh0): stage A-half0 of kt+1
    rdA(0); rdB(0);
    if (pf) { stA(nb, 0, 0, kt + 1); stA(nb, 0, 1, kt + 1); }
    BAR(); WAIT_LGKM0;
    __builtin_amdgcn_s_setprio(1);
#pragma unroll
    for (int ks = 0; ks < 2; ++ks)
#pragma unroll
      for (int mf = 0; mf < 4; ++mf)
#pragma unroll
        for (int nf = 0; nf < 2; ++nf) MFMA16(acc[mf][nf], a[mf][ks], b[nf][ks]);
    __builtin_amdgcn_s_setprio(0);
    if (pf) { WAIT_VM4; } else { WAIT_VM2; }
    BAR();

    // ---- PH2 (mh0,nh1): stage B-half0
    rdB(1);
    if (pf) { stB(nb, 0, 0, kt + 1); stB(nb, 0, 1, kt + 1); }
    BAR(); WAIT_LGKM0;
    __builtin_amdgcn_s_setprio(1);
#pragma unroll
    for (int ks = 0; ks < 2; ++ks)
#pragma unroll
      for (int mf = 0; mf < 4; ++mf)
#pragma unroll
        for (int nf = 0; nf < 2; ++nf) MFMA16(acc[mf][2 + nf], a[mf][ks], b[nf][ks]);
    __builtin_amdgcn_s_setprio(0);
    if (pf) { WAIT_VM4; } else { WAIT_VM0; }
    BAR();

    // ---- PH3 (mh1,nh0): stage B-half1
    rdA(1); rdB(0);
    if (pf) { stB(nb, 1, 0, kt + 1); stB(nb, 1, 1, kt + 1); }
    BAR(); WAIT_LGKM0;
    __builtin_amdgcn_s_setprio(1);
#pragma unroll
    for (int ks = 0; ks < 2; ++ks)
#pragma unroll
      for (int mf = 0; mf < 4; ++mf)
#pragma unroll
        for (int nf = 0; nf < 2; ++nf) MFMA16(acc[4 + mf][nf], a[mf][ks], b[nf][ks]);
    __builtin_amdgcn_s_setprio(0);
    BAR();

    // ---- PH4 (mh1,nh1): stage A-half1
    rdB(1);
    if (pf) { stA(nb, 1, 0, kt + 1); stA(nb, 1, 1, kt + 1); }
    BAR(); WAIT_LGKM0;
    __builtin_amdgcn_s_setprio(1);
#pragma unroll
    for (int ks = 0; ks < 2; ++ks)
#pragma unroll
      for (int mf = 0; mf < 4; ++mf)
#pragma unroll
        for (int nf = 0; nf < 2; ++nf) MFMA16(acc[4 + mf][2 + nf], a[mf][ks], b[nf][ks]);
    __builtin_amdgcn_s_setprio(0);
    if (pf) { WAIT_VM4; }
    BAR();
  }

  // epilogue: bias + relu + bf16 (interleaved frag rows: mf8*32 + wm*16)
#pragma unroll
  for (int nf = 0; nf < 4; ++nf) {
    const int colIn = nBase + nf * 64 + wn * 16 + lr;
    const float bv = biasE[nf * 64 + wn * 16 + lr];
#pragma unroll
    for (int mf = 0; mf < 8; ++mf) {
      const int row0 = mBase + mf * 32 + wm * 16 + lk * 4;
#pragma unroll
      for (int j = 0; j < 4; ++j) {
        float v = acc[mf][nf][j] + bv;
        v = v > 0.f ? v : 0.f;
        C0[(size_t)(row0 + j) * 1024 + colIn] = __float2bfloat16(v);
      }
    }
  }
}

// ---------------------------------------------------------------- L3 + softmax + scatter
__global__ __launch_bounds__(256) void gemm2_softmax_kernel(
    const bf16* __restrict__ h1, const bf16* __restrict__ W2b,
    const float* __restrict__ ltl, const int* __restrict__ lidx,
    const int* __restrict__ aidx, float* __restrict__ outp, int mGlobBase, int MC) {
  __shared__ short lsA[2][32 * 64];
  __shared__ short lsB[2][64 * 64];
  __shared__ float X[32][68];
  __shared__ int s_lidx[32];
  __shared__ int s_inv[64];
  __shared__ int s_arow;
  const int a = blockIdx.y;
  const bf16* Ain = h1 + (size_t)a * MC * Hdim;
  const bf16* Bw = W2b + (size_t)a * Pdim * Hdim;
  const float* ltlE = ltl + (size_t)a * Pdim;

  const int t = threadIdx.x;
  const int mBase = blockIdx.x * 32;
  const int w = t >> 6, lane = t & 63;
  const int lr = lane & 15, lk = lane >> 4;
  const int wr = w & 1, wq = w >> 1;

  if (t < 64) s_inv[t] = -1;
  __syncthreads();
  if (t < 32) {
    int q = lidx[t];
    s_lidx[t] = q;
    s_inv[q] = t;
  }
  if (t == 0) s_arow = aidx[a];
  __syncthreads();

  const int srow = t >> 3;
  const int sg = (t & 7) ^ ((t >> 3) & 7);
  const bf16* gA = Ain + (size_t)(mBase + srow) * Hdim + sg * 8;
  const bf16* gB = Bw + (size_t)srow * Hdim + sg * 8;

  auto stage = [&](int buf, int kt) {
    gload_lds16(gA + kt * 64, &lsA[buf][t * 8]);
    gload_lds16(gB + kt * 64, &lsB[buf][t * 8]);
    gload_lds16(gB + (size_t)32 * Hdim + kt * 64, &lsB[buf][2048 + t * 8]);
  };

  v4f acc[2];
  acc[0] = (v4f)(0.f); acc[1] = (v4f)(0.f);

  stage(0, 0);
  for (int kt = 0; kt < 16; ++kt) {
    const int buf = kt & 1;
    if (kt + 1 < 16) { stage(buf ^ 1, kt + 1); WAIT_VM3; } else { WAIT_VM0; }
    BAR();
#pragma unroll
    for (int s = 0; s < 2; ++s) {
      int rowA = wr * 16 + lr;
      v8s af = *(const v8s*)&lsA[buf][rowA * 64 + ((((s << 2) + lk) ^ (rowA & 7)) << 3)];
#pragma unroll
      for (int n = 0; n < 2; ++n) {
        int rowB = wq * 32 + n * 16 + lr;
        v8s bf = *(const v8s*)&lsB[buf][rowB * 64 + ((((s << 2) + lk) ^ (rowB & 7)) << 3)];
        MFMA16(acc[n], af, bf);
      }
    }
    BAR();
  }

#pragma unroll
  for (int n = 0; n < 2; ++n) {
    const int col = wq * 32 + n * 16 + lr;
    const float lc = ltlE[col];
#pragma unroll
    for (int j = 0; j < 4; ++j) {
      X[wr * 16 + lk * 4 + j][col] = acc[n][j] + lc;
    }
  }
  __syncthreads();

  if (t < 32) {
    const int r = t;
    float mx = -1e30f;
#pragma unroll
    for (int l = 0; l < 32; ++l) mx = fmaxf(mx, X[r][s_lidx[l]]);
    float s = 0.f;
#pragma unroll
    for (int l = 0; l < 32; ++l) s += __expf(X[r][s_lidx[l]] - mx);
    const float rs = 1.f / s;
    const size_t obase = ((size_t)(mGlobBase + mBase + r) * 64 + s_arow) * 64;
#pragma unroll
    for (int q0 = 0; q0 < 64; q0 += 4) {
      float4 v;
      v.x = (s_inv[q0 + 0] >= 0) ? __expf(X[r][q0 + 0] - mx) * rs : 0.f;
      v.y = (s_inv[q0 + 1] >= 0) ? __expf(X[r][q0 + 1] - mx) * rs : 0.f;
      v.z = (s_inv[q0 + 2] >= 0) ? __expf(X[r][q0 + 2] - mx) * rs : 0.f;
      v.w = (s_inv[q0 + 3] >= 0) ? __expf(X[r][q0 + 3] - mx) * rs : 0.f;
      *(float4*)&outp[obase + q0] = v;
    }
  }
}

// ---------------------------------------------------------------- launch
extern "C" void kernel_launch(void* const* d_in, const int* in_sizes, int n_in,
                              void* d_out, int out_size, void* d_ws, size_t ws_size,
                              hipStream_t stream) {
  const float* state = (const float*)d_in[0];
  const float* W0 = (const float*)d_in[1];
  const float* b0 = (const float*)d_in[2];
  const float* W1 = (const float*)d_in[3];
  const float* b1 = (const float*)d_in[4];
  const float* W2 = (const float*)d_in[5];
  const float* ltl = (const float*)d_in[6];
  const int* lidx = (const int*)d_in[7];
  const int* aidx = (const int*)d_in[8];
  float* outp = (float*)d_out;

  char* ws = (char*)d_ws;
  bf16* stateb = (bf16*)ws;
  bf16* W0b = stateb + (size_t)Mtot * Fdim;
  bf16* W1b = W0b + (size_t)Aexp * Hdim * Fdim;
  bf16* W2b = W1b + (size_t)Aexp * Hdim * Hdim;
  bf16* h0 = W2b + (size_t)Aexp * Pdim * Hdim;
  const size_t fixedB = (size_t)(Mtot * Fdim + Aexp * Hdim * Fdim +
                                 Aexp * Hdim * Hdim + Aexp * Pdim * Hdim) * 2;
  int MC = 2048;
  while (MC > 512 && fixedB + (size_t)2 * Aexp * MC * Hdim * 2 + 4096 > ws_size) MC >>= 1;
  bf16* h1 = h0 + (size_t)Aexp * MC * Hdim;

  ident_kernel<<<dim3(4096), dim3(256), 0, stream>>>(outp);
  cvt_all_kernel<<<dim3(2048), dim3(256), 0, stream>>>(
      state, (unsigned short*)stateb, Mtot * Fdim / 4,
      W0, (unsigned short*)W0b, Aexp * Hdim * Fdim / 4,
      W1, (unsigned short*)W1b, Aexp * Hdim * Hdim / 4,
      W2, (unsigned short*)W2b, Aexp * Pdim * Hdim / 4);

  const int nbm = MC / 256;
  for (int mOff = 0; mOff < Mtot; mOff += MC) {
    // L1: h0[a][MC][1024] = relu(state[MC,512] @ W0[a][1024,512]^T + b0[a])
    gemm256_kernel<Fdim / 64><<<dim3(nbm * 4 * Aexp), dim3(512), 0, stream>>>(
        stateb + (size_t)mOff * Fdim, 0L,
        W0b, b0, h0, (long)MC * Hdim, nbm);
    // L2: h1[a][MC][1024] = relu(h0[a] @ W1[a][1024,1024]^T + b1[a])
    gemm256_kernel<Hdim / 64><<<dim3(nbm * 4 * Aexp), dim3(512), 0, stream>>>(
        h0, (long)MC * Hdim,
        W1b, b1, h1, (long)MC * Hdim, nbm);
    // L3 + softmax + scatter
    gemm2_softmax_kernel<<<dim3(MC / 32, Aexp), dim3(256), 0, stream>>>(
        h1, W2b, ltl, lidx, aidx, outp, mOff, MC);
  }
}